// Round 2
// baseline (247.035 us; speedup 1.0000x reference)
//
#include <hip/hip_runtime.h>
#include <hip/hip_bf16.h>

// Problem constants (from reference)
constexpr int B = 8;
constexpr int L = 2048;
constexpr int ANG = 16;
constexpr int AMP = 48;
constexpr int H = 4;
constexpr int AQK = 12, GQK = 6;
constexpr int AV = 12, GV = 6;
constexpr int HD = 2 * GQK + AQK;      // 24 = per-head q/k/v dim
constexpr int LOOKBACK = 100;

constexpr int TQ = 128;                 // queries per block in attention
constexpr int MAXK = TQ + LOOKBACK - 1; // 227 key rows max per tile
constexpr int KPAD = 25;                // row stride in LDS (25 coprime w/ 32 banks)

// -------------------- Kernel 1: fused QKV projections --------------------
// One thread per (token, head, d) computes q,k,v element (3 dot products).
__global__ __launch_bounds__(256) void qkv_kernel(
    const float* __restrict__ x_ang, const float* __restrict__ x_amp,
    const float* __restrict__ Wq_amp, const float* __restrict__ Wk_amp,
    const float* __restrict__ Wv_amp,
    const float* __restrict__ Wq_ang_r, const float* __restrict__ Wq_ang_i,
    const float* __restrict__ Wk_ang_r, const float* __restrict__ Wk_ang_i,
    const float* __restrict__ Wv_ang_r, const float* __restrict__ Wv_ang_i,
    float* __restrict__ q, float* __restrict__ k, float* __restrict__ v)
{
    const int TOT = B * L * H * HD;
    int idx = blockIdx.x * blockDim.x + threadIdx.x;
    if (idx >= TOT) return;

    int d   = idx % HD;
    int h   = (idx / HD) % H;
    int tok = idx / (H * HD);           // b*L + l

    const float* xa = x_ang + (size_t)tok * (2 * ANG); // [0:16]=real, [16:32]=imag
    const float* xm = x_amp + (size_t)tok * AMP;

    float aq = 0.f, ak = 0.f, av = 0.f;
    if (d < 2 * GQK) {
        // angular part (complex linear): d<6 -> real, 6<=d<12 -> imag
        int  dd   = (d < GQK) ? d : d - GQK;
        int  col  = h * GQK + dd;
        bool imag = (d >= GQK);
        #pragma unroll
        for (int i = 0; i < ANG; i++) {
            float xr = xa[i], xi = xa[ANG + i];
            float qwr = Wq_ang_r[i * (H * GQK) + col], qwi = Wq_ang_i[i * (H * GQK) + col];
            float kwr = Wk_ang_r[i * (H * GQK) + col], kwi = Wk_ang_i[i * (H * GQK) + col];
            float vwr = Wv_ang_r[i * (H * GQK) + col], vwi = Wv_ang_i[i * (H * GQK) + col];
            if (!imag) {
                aq += xr * qwr - xi * qwi;
                ak += xr * kwr - xi * kwi;
                av += xr * vwr - xi * vwi;
            } else {
                aq += xr * qwi + xi * qwr;
                ak += xr * kwi + xi * kwr;
                av += xr * vwi + xi * vwr;
            }
        }
    } else {
        // amplitude part
        int col = h * AQK + (d - 2 * GQK);
        #pragma unroll 8
        for (int i = 0; i < AMP; i++) {
            float x = xm[i];
            aq += x * Wq_amp[i * (H * AQK) + col];
            ak += x * Wk_amp[i * (H * AQK) + col];
            av += x * Wv_amp[i * (H * AV)  + col];
        }
    }

    int b = tok / L, l = tok % L;
    size_t out_idx = (((size_t)b * H + h) * L + l) * HD + d;
    q[out_idx] = aq;
    k[out_idx] = ak;
    v[out_idx] = av;
}

// -------------------- Kernel 2: banded causal attention --------------------
// Block handles (b,h, 128-query tile). Thread per query, online softmax over
// <=100 keys read from LDS-staged K/V tile (row stride 25 -> conflict-free).
__global__ __launch_bounds__(TQ) void attn_kernel(
    const float* __restrict__ q, const float* __restrict__ k,
    const float* __restrict__ v, float* __restrict__ att)
{
    constexpr int NT = L / TQ; // tiles per (b,h)
    int bh = blockIdx.x / NT;
    int qt = blockIdx.x % NT;
    int q0 = qt * TQ;
    int kmin = q0 - (LOOKBACK - 1); if (kmin < 0) kmin = 0;
    int kmax = q0 + TQ - 1;        // always < L (L % TQ == 0)
    int nrows = kmax - kmin + 1;   // <= MAXK

    __shared__ float Ks[MAXK][KPAD];
    __shared__ float Vs[MAXK][KPAD];

    const float* kbase = k + (size_t)bh * L * HD;
    const float* vbase = v + (size_t)bh * L * HD;
    for (int e = threadIdx.x; e < nrows * HD; e += blockDim.x) {
        int r = e / HD, c = e % HD;
        size_t g = (size_t)(kmin + r) * HD + c;
        Ks[r][c] = kbase[g];
        Vs[r][c] = vbase[g];
    }
    __syncthreads();

    const int qi = q0 + threadIdx.x;
    const float* qp = q + ((size_t)bh * L + qi) * HD;
    float qr[HD];
    #pragma unroll
    for (int d = 0; d < HD; d++) qr[d] = qp[d];

    const float scale = 0.2041241452319315f; // 1/sqrt(24)
    float m = -3.0e38f, s = 0.f;
    float o[HD];
    #pragma unroll
    for (int d = 0; d < HD; d++) o[d] = 0.f;

    int j0 = qi - (LOOKBACK - 1); if (j0 < 0) j0 = 0;
    for (int j = j0; j <= qi; j++) {
        int r = j - kmin;
        float sc = 0.f;
        #pragma unroll
        for (int d = 0; d < HD; d++) sc += qr[d] * Ks[r][d];
        sc *= scale;
        float mn   = fmaxf(m, sc);
        float corr = __expf(m - mn);
        float p    = __expf(sc - mn);
        s = s * corr + p;
        #pragma unroll
        for (int d = 0; d < HD; d++) o[d] = o[d] * corr + p * Vs[r][d];
        m = mn;
    }
    float inv = 1.f / s;
    float* op = att + ((size_t)bh * L + qi) * HD;
    #pragma unroll
    for (int d = 0; d < HD; d++) op[d] = o[d] * inv;
}

// -------------------- Kernel 3: output projections --------------------
// Thread per (token, one of 80 output scalars). Outputs concatenated:
// [0 : B*L*16)             out_ang_r
// [B*L*16 : 2*B*L*16)      out_ang_i
// [2*B*L*16 : ... )        out_amp (48 per token)
__global__ __launch_bounds__(256) void proj_kernel(
    const float* __restrict__ att,
    const float* __restrict__ Wout_amp, const float* __restrict__ bout_amp,
    const float* __restrict__ Wout_ang_r, const float* __restrict__ Wout_ang_i,
    float* __restrict__ out)
{
    const int TOT = B * L * 80;
    int idx = blockIdx.x * blockDim.x + threadIdx.x;
    if (idx >= TOT) return;

    int o   = idx % 80;
    int tok = idx / 80;
    int b = tok / L, l = tok % L;
    const float* abase = att + ((size_t)b * H * L + l) * HD; // +h*L*HD for head h

    constexpr size_t ANG_OUT = (size_t)B * L * ANG; // 262144

    if (o < 2 * ANG) {
        bool imag = (o >= ANG);
        int  col  = imag ? (o - ANG) : o;
        float acc = 0.f;
        #pragma unroll
        for (int h = 0; h < H; h++) {
            const float* a = abase + (size_t)h * L * HD;
            #pragma unroll
            for (int dd = 0; dd < GV; dd++) {
                float ar = a[dd], ai = a[GV + dd];
                int row = h * GV + dd;
                float wr = Wout_ang_r[row * ANG + col];
                float wi = Wout_ang_i[row * ANG + col];
                if (!imag) acc += ar * wr - ai * wi;
                else       acc += ar * wi + ai * wr;
            }
        }
        out[(imag ? ANG_OUT : 0) + (size_t)tok * ANG + col] = acc;
    } else {
        int col = o - 2 * ANG; // 0..47
        float acc = bout_amp[col];
        #pragma unroll
        for (int h = 0; h < H; h++) {
            const float* a = abase + (size_t)h * L * HD + 2 * GV;
            #pragma unroll
            for (int dd = 0; dd < AV; dd++) {
                acc += a[dd] * Wout_amp[(h * AV + dd) * AMP + col];
            }
        }
        out[2 * ANG_OUT + (size_t)tok * AMP + col] = acc;
    }
}

// -------------------- Launch --------------------
extern "C" void kernel_launch(void* const* d_in, const int* in_sizes, int n_in,
                              void* d_out, int out_size, void* d_ws, size_t ws_size,
                              hipStream_t stream)
{
    const float* x_ang      = (const float*)d_in[0];
    const float* x_amp      = (const float*)d_in[1];
    const float* Wq_amp     = (const float*)d_in[2];
    const float* Wk_amp     = (const float*)d_in[3];
    const float* Wv_amp     = (const float*)d_in[4];
    const float* Wq_ang_r   = (const float*)d_in[5];
    const float* Wq_ang_i   = (const float*)d_in[6];
    const float* Wk_ang_r   = (const float*)d_in[7];
    const float* Wk_ang_i   = (const float*)d_in[8];
    const float* Wv_ang_r   = (const float*)d_in[9];
    const float* Wv_ang_i   = (const float*)d_in[10];
    const float* Wout_amp   = (const float*)d_in[11];
    const float* bout_amp   = (const float*)d_in[12];
    const float* Wout_ang_r = (const float*)d_in[13];
    const float* Wout_ang_i = (const float*)d_in[14];

    float* out = (float*)d_out;
    float* ws  = (float*)d_ws;

    const size_t N = (size_t)B * H * L * HD; // 1,572,864 floats per buffer
    float* q   = ws;
    float* k   = ws + N;
    float* v   = ws + 2 * N;
    float* att = ws + 3 * N;

    // K1: QKV
    {
        int tot = B * L * H * HD;
        qkv_kernel<<<(tot + 255) / 256, 256, 0, stream>>>(
            x_ang, x_amp, Wq_amp, Wk_amp, Wv_amp,
            Wq_ang_r, Wq_ang_i, Wk_ang_r, Wk_ang_i, Wv_ang_r, Wv_ang_i,
            q, k, v);
    }
    // K2: banded attention
    {
        int nblocks = B * H * (L / TQ); // 512
        attn_kernel<<<nblocks, TQ, 0, stream>>>(q, k, v, att);
    }
    // K3: output projections
    {
        int tot = B * L * 80;
        proj_kernel<<<(tot + 255) / 256, 256, 0, stream>>>(
            att, Wout_amp, bout_amp, Wout_ang_r, Wout_ang_i, out);
    }
}

// Round 3
// 153.170 us; speedup vs baseline: 1.6128x; 1.6128x over previous
//
#include <hip/hip_runtime.h>
#include <hip/hip_bf16.h>

// Problem constants (from reference)
constexpr int B = 8;
constexpr int L = 2048;
constexpr int ANG = 16;
constexpr int AMP = 48;
constexpr int H = 4;
constexpr int AQK = 12, GQK = 6;
constexpr int AV = 12, GV = 6;
constexpr int HD = 2 * GQK + AQK;      // 24 = per-head q/k/v dim
constexpr int LOOKBACK = 100;

constexpr int NTOK = B * L;            // 16384 tokens

// -------------------- Kernel 1: fused QKV projections --------------------
// Role is chosen PER BLOCK so every wave is uniform (no divergence):
//   blocks [0, AMP_BLOCKS):   thread = (token, col in [0,48)) -> q,k,v amp
//   blocks [AMP_BLOCKS, ...): thread = (token, job in [0,72)) -> one of
//                             {q,k,v} x (h,dd) complex output pair (r,i)
constexpr int QKV_AMP_JOBS = NTOK * 48;              // 786432
constexpr int QKV_ANG_JOBS = NTOK * 72;              // 1179648
constexpr int QKV_AMP_BLOCKS = QKV_AMP_JOBS / 256;   // 3072
constexpr int QKV_ANG_BLOCKS = QKV_ANG_JOBS / 256;   // 4608

__global__ __launch_bounds__(256) void qkv2_kernel(
    const float* __restrict__ x_ang, const float* __restrict__ x_amp,
    const float* __restrict__ Wq_amp, const float* __restrict__ Wk_amp,
    const float* __restrict__ Wv_amp,
    const float* __restrict__ Wq_ang_r, const float* __restrict__ Wq_ang_i,
    const float* __restrict__ Wk_ang_r, const float* __restrict__ Wk_ang_i,
    const float* __restrict__ Wv_ang_r, const float* __restrict__ Wv_ang_i,
    float* __restrict__ q, float* __restrict__ k, float* __restrict__ v)
{
    int bid = blockIdx.x;
    if (bid < QKV_AMP_BLOCKS) {
        int g   = bid * 256 + threadIdx.x;
        int col = g % 48;               // h*12 + ca
        int tok = g / 48;

        // stage x_amp[tok] into registers via float4 (48 floats, aligned 192B)
        const float4* xm4 = (const float4*)(x_amp + (size_t)tok * AMP);
        float x[48];
        #pragma unroll
        for (int i = 0; i < 12; i++) {
            float4 t = xm4[i];
            x[4*i+0] = t.x; x[4*i+1] = t.y; x[4*i+2] = t.z; x[4*i+3] = t.w;
        }

        float aq = 0.f, ak = 0.f, av = 0.f;
        #pragma unroll
        for (int i = 0; i < 48; i++) {
            aq += x[i] * Wq_amp[i * 48 + col];
            ak += x[i] * Wk_amp[i * 48 + col];
            av += x[i] * Wv_amp[i * 48 + col];
        }

        int b = tok / L, l = tok % L;
        int h = col / 12, ca = col % 12;
        size_t o = (((size_t)b * H + h) * L + l) * HD + (2 * GQK) + ca;
        q[o] = aq; k[o] = ak; v[o] = av;
    } else {
        int g     = (bid - QKV_AMP_BLOCKS) * 256 + threadIdx.x;
        int j     = g % 72;
        int tok   = g / 72;
        int mat   = j / 24;             // 0=q 1=k 2=v
        int combo = j % 24;             // = weight col = h*6+dd
        int h     = combo / 6, dd = combo % 6;

        const float4* xa4 = (const float4*)(x_ang + (size_t)tok * (2 * ANG));
        float xr[16], xi[16];
        #pragma unroll
        for (int i = 0; i < 4; i++) {
            float4 t = xa4[i];
            xr[4*i+0] = t.x; xr[4*i+1] = t.y; xr[4*i+2] = t.z; xr[4*i+3] = t.w;
            float4 u = xa4[4 + i];
            xi[4*i+0] = u.x; xi[4*i+1] = u.y; xi[4*i+2] = u.z; xi[4*i+3] = u.w;
        }

        const float* Wr = (mat == 0) ? Wq_ang_r : (mat == 1) ? Wk_ang_r : Wv_ang_r;
        const float* Wi = (mat == 0) ? Wq_ang_i : (mat == 1) ? Wk_ang_i : Wv_ang_i;

        float orr = 0.f, oii = 0.f;
        #pragma unroll
        for (int i = 0; i < 16; i++) {
            float wr = Wr[i * 24 + combo], wi = Wi[i * 24 + combo];
            orr += xr[i] * wr - xi[i] * wi;
            oii += xr[i] * wi + xi[i] * wr;
        }

        float* dst = (mat == 0) ? q : (mat == 1) ? k : v;
        int b = tok / L, l = tok % L;
        size_t base = (((size_t)b * H + h) * L + l) * HD;
        dst[base + dd]       = orr;
        dst[base + GQK + dd] = oii;
    }
}

// -------------------- Kernel 2: banded causal attention --------------------
// Block = (b,h, 128-query tile), 256 threads = 2 wave-groups.
// Group g handles keys j = j0+g, j0+g+2, ... (parity split-K); partials
// merged via LDS with exact online-softmax algebra.
constexpr int TQ   = 128;
constexpr int MAXK = TQ + LOOKBACK - 1; // 227
constexpr int KP   = 28;                // row stride: 112B, 16B-aligned for b128

__global__ __launch_bounds__(256) void attn2_kernel(
    const float* __restrict__ q, const float* __restrict__ k,
    const float* __restrict__ v, float* __restrict__ att)
{
    constexpr int NT = L / TQ;
    int bh = blockIdx.x / NT;
    int qt = blockIdx.x % NT;
    int q0 = qt * TQ;
    int kmin = q0 - (LOOKBACK - 1); if (kmin < 0) kmin = 0;
    int nrows = (q0 + TQ - 1) - kmin + 1;

    __shared__ float Ks[MAXK][KP];
    __shared__ float Vs[MAXK][KP];
    __shared__ float Pm[TQ], Ps[TQ];
    __shared__ float Po[TQ][25];

    // stage K/V rows [kmin, kmin+nrows) as float4 (rows are 96B-aligned)
    {
        const float4* kb4 = (const float4*)(k + ((size_t)bh * L + kmin) * HD);
        const float4* vb4 = (const float4*)(v + ((size_t)bh * L + kmin) * HD);
        int nch = nrows * 6;
        for (int c = threadIdx.x; c < nch; c += 256) {
            int r = c / 6, s = c % 6;
            *(float4*)&Ks[r][s * 4] = kb4[c];
            *(float4*)&Vs[r][s * 4] = vb4[c];
        }
    }
    __syncthreads();

    int qlocal = threadIdx.x & (TQ - 1);
    int group  = threadIdx.x >> 7;      // 0 or 1
    int qi = q0 + qlocal;

    float qr[HD];
    {
        const float4* qp4 = (const float4*)(q + ((size_t)bh * L + qi) * HD);
        #pragma unroll
        for (int i = 0; i < 6; i++) {
            float4 t = qp4[i];
            qr[4*i+0] = t.x; qr[4*i+1] = t.y; qr[4*i+2] = t.z; qr[4*i+3] = t.w;
        }
    }

    const float scale = 0.2041241452319315f; // 1/sqrt(24)
    float m = -3.0e38f, s = 0.f;
    float o[HD];
    #pragma unroll
    for (int d = 0; d < HD; d++) o[d] = 0.f;

    int j0 = qi - (LOOKBACK - 1); if (j0 < 0) j0 = 0;
    for (int j = j0 + group; j <= qi; j += 2) {
        int r = j - kmin;
        float sc = 0.f;
        #pragma unroll
        for (int d = 0; d < HD; d++) sc += qr[d] * Ks[r][d];
        sc *= scale;
        float mn   = fmaxf(m, sc);
        float corr = __expf(m - mn);
        float p    = __expf(sc - mn);
        s = s * corr + p;
        #pragma unroll
        for (int d = 0; d < HD; d++) o[d] = o[d] * corr + p * Vs[r][d];
        m = mn;
    }

    if (group == 0) {
        Pm[qlocal] = m; Ps[qlocal] = s;
        #pragma unroll
        for (int d = 0; d < HD; d++) Po[qlocal][d] = o[d];
    }
    __syncthreads();
    if (group == 1) {
        float m2 = Pm[qlocal], s2 = Ps[qlocal];
        float mm = fmaxf(m, m2);
        float c1 = __expf(m - mm), c2 = __expf(m2 - mm);
        float inv = 1.f / (s * c1 + s2 * c2);
        float* op = att + ((size_t)bh * L + qi) * HD;
        #pragma unroll
        for (int d = 0; d < HD; d++)
            op[d] = (o[d] * c1 + Po[qlocal][d] * c2) * inv;
    }
}

// -------------------- Kernel 3: output projections --------------------
// Per-block role split again:
//   blocks [0, PAMP_BLOCKS):  thread = (token, col in [0,48)) -> out_amp
//   blocks [PAMP_BLOCKS,...): thread = (token, col in [0,16)) -> out_ang r&i
constexpr int PAMP_JOBS   = NTOK * 48;             // 786432
constexpr int PANG_JOBS   = NTOK * 16;             // 262144
constexpr int PAMP_BLOCKS = PAMP_JOBS / 256;       // 3072
constexpr int PANG_BLOCKS = PANG_JOBS / 256;       // 1024

__global__ __launch_bounds__(256) void proj2_kernel(
    const float* __restrict__ att,
    const float* __restrict__ Wout_amp, const float* __restrict__ bout_amp,
    const float* __restrict__ Wout_ang_r, const float* __restrict__ Wout_ang_i,
    float* __restrict__ out)
{
    constexpr size_t ANG_OUT = (size_t)NTOK * ANG; // 262144
    int bid = blockIdx.x;

    if (bid < PAMP_BLOCKS) {
        int g   = bid * 256 + threadIdx.x;
        int col = g % 48;
        int tok = g / 48;
        int b = tok / L, l = tok % L;

        // gather amp slice of att: per head, floats [12..24) -> 3 float4
        float a[48];
        #pragma unroll
        for (int h = 0; h < H; h++) {
            const float4* ap4 = (const float4*)(att + (((size_t)b * H + h) * L + l) * HD + 2 * GV);
            #pragma unroll
            for (int i = 0; i < 3; i++) {
                float4 t = ap4[i];
                a[h*12 + 4*i+0] = t.x; a[h*12 + 4*i+1] = t.y;
                a[h*12 + 4*i+2] = t.z; a[h*12 + 4*i+3] = t.w;
            }
        }
        float acc = bout_amp[col];
        #pragma unroll
        for (int i = 0; i < 48; i++)
            acc += a[i] * Wout_amp[i * AMP + col];
        out[2 * ANG_OUT + (size_t)tok * AMP + col] = acc;
    } else {
        int g   = (bid - PAMP_BLOCKS) * 256 + threadIdx.x;
        int col = g % 16;
        int tok = g / 16;
        int b = tok / L, l = tok % L;

        // gather ang slice of att: per head, floats [0..12) -> 3 float4
        float ar[24], ai[24];
        #pragma unroll
        for (int h = 0; h < H; h++) {
            const float4* ap4 = (const float4*)(att + (((size_t)b * H + h) * L + l) * HD);
            float4 t0 = ap4[0], t1 = ap4[1], t2 = ap4[2];
            ar[h*6+0] = t0.x; ar[h*6+1] = t0.y; ar[h*6+2] = t0.z; ar[h*6+3] = t0.w;
            ar[h*6+4] = t1.x; ar[h*6+5] = t1.y;
            ai[h*6+0] = t1.z; ai[h*6+1] = t1.w;
            ai[h*6+2] = t2.x; ai[h*6+3] = t2.y; ai[h*6+4] = t2.z; ai[h*6+5] = t2.w;
        }
        float accr = 0.f, acci = 0.f;
        #pragma unroll
        for (int i = 0; i < 24; i++) {
            float wr = Wout_ang_r[i * ANG + col], wi = Wout_ang_i[i * ANG + col];
            accr += ar[i] * wr - ai[i] * wi;
            acci += ar[i] * wi + ai[i] * wr;
        }
        out[(size_t)tok * ANG + col]           = accr;
        out[ANG_OUT + (size_t)tok * ANG + col] = acci;
    }
}

// -------------------- Launch --------------------
extern "C" void kernel_launch(void* const* d_in, const int* in_sizes, int n_in,
                              void* d_out, int out_size, void* d_ws, size_t ws_size,
                              hipStream_t stream)
{
    const float* x_ang      = (const float*)d_in[0];
    const float* x_amp      = (const float*)d_in[1];
    const float* Wq_amp     = (const float*)d_in[2];
    const float* Wk_amp     = (const float*)d_in[3];
    const float* Wv_amp     = (const float*)d_in[4];
    const float* Wq_ang_r   = (const float*)d_in[5];
    const float* Wq_ang_i   = (const float*)d_in[6];
    const float* Wk_ang_r   = (const float*)d_in[7];
    const float* Wk_ang_i   = (const float*)d_in[8];
    const float* Wv_ang_r   = (const float*)d_in[9];
    const float* Wv_ang_i   = (const float*)d_in[10];
    const float* Wout_amp   = (const float*)d_in[11];
    const float* bout_amp   = (const float*)d_in[12];
    const float* Wout_ang_r = (const float*)d_in[13];
    const float* Wout_ang_i = (const float*)d_in[14];

    float* out = (float*)d_out;
    float* ws  = (float*)d_ws;

    const size_t N = (size_t)B * H * L * HD; // 1,572,864 floats per buffer
    float* q   = ws;
    float* k   = ws + N;
    float* v   = ws + 2 * N;
    float* att = ws + 3 * N;

    qkv2_kernel<<<QKV_AMP_BLOCKS + QKV_ANG_BLOCKS, 256, 0, stream>>>(
        x_ang, x_amp, Wq_amp, Wk_amp, Wv_amp,
        Wq_ang_r, Wq_ang_i, Wk_ang_r, Wk_ang_i, Wv_ang_r, Wv_ang_i,
        q, k, v);

    attn2_kernel<<<B * H * (L / TQ), 256, 0, stream>>>(q, k, v, att);

    proj2_kernel<<<PAMP_BLOCKS + PANG_BLOCKS, 256, 0, stream>>>(
        att, Wout_amp, bout_amp, Wout_ang_r, Wout_ang_i, out);
}